// Round 1
// baseline (459.765 us; speedup 1.0000x reference)
//
#include <hip/hip_runtime.h>
#include <hip/hip_bf16.h>
#include <stdint.h>

using sh8    = __attribute__((ext_vector_type(8))) short;
using f32x4  = __attribute__((ext_vector_type(4))) float;
using f32x16 = __attribute__((ext_vector_type(16))) float;

#define MFMA16(a, b, c) __builtin_amdgcn_mfma_f32_16x16x32_bf16(a, b, c, 0, 0, 0)
#define EXP2F(x) __builtin_amdgcn_exp2f(x)
#define SBAR()  __builtin_amdgcn_s_barrier()
#define PRIO1() __builtin_amdgcn_s_setprio(1)
#define PRIO0() __builtin_amdgcn_s_setprio(0)
// raw-barrier schedule: drain LDS reads before the MFMA cluster (template m201).
#define WAITL() asm volatile("s_waitcnt lgkmcnt(0)" ::: "memory")

static constexpr int BB = 32, SS = 577, HH = 16;
static constexpr int MM = BB * SS;     // 18464 rows (b,s)
static constexpr int SPAD = 640;       // padded S for V^T buffer
// attention scale folded into Wq, in log2 domain: D^-0.5 * log2(e)
static constexpr float QSCALE = 0.18033688011112042f;

__device__ __forceinline__ ushort f2b(float f) {
  union { float f; uint32_t u; } v{f};
  uint32_t r = v.u + 0x7FFFu + ((v.u >> 16) & 1u);   // RNE
  return (ushort)(r >> 16);
}

#if __has_builtin(__builtin_amdgcn_cvt_pk_bf16_f32)
typedef __attribute__((ext_vector_type(2))) __bf16 bf16x2_t;
__device__ __forceinline__ uint32_t pk_bf16(float a, float b) {
  union { bf16x2_t v; uint32_t u; } c;
  c.v = __builtin_amdgcn_cvt_pk_bf16_f32(a, b);
  return c.u;
}
#else
__device__ __forceinline__ uint32_t pk_bf16(float a, float b) {
  return (uint32_t)f2b(a) | ((uint32_t)f2b(b) << 16);
}
#endif

// async global->LDS, 16B per lane. LDS dest is wave-uniform base + lane*16.
__device__ __forceinline__ void gld16(const ushort* g, ushort* l) {
  __builtin_amdgcn_global_load_lds(
      (const __attribute__((address_space(1))) uint32_t*)g,
      (__attribute__((address_space(3))) uint32_t*)l, 16, 0, 0);
}

// ---------------- converts (x and Wo fused in one launch) ----------------
__global__ __launch_bounds__(256)
void convert2_f32_bf16(const float* __restrict__ a, ushort* __restrict__ oa, int na4,
                       const float* __restrict__ b, ushort* __restrict__ ob, int nb4) {
  const int total = na4 + nb4;
  const int stride = gridDim.x * 256;
  for (int i = blockIdx.x * 256 + threadIdx.x; i < total; i += stride) {
    const float4 f = (i < na4) ? ((const float4*)a)[i] : ((const float4*)b)[i - na4];
    ushort4 u;
    u.x = f2b(f.x); u.y = f2b(f.y); u.z = f2b(f.z); u.w = f2b(f.w);
    if (i < na4) ((ushort4*)oa)[i] = u;
    else         ((ushort4*)ob)[i - na4] = u;
  }
}

// Wt[n][k], n = sel*1024 + h*64 + d  (B^T layout), k = e.  LDS-tiled transpose.
// Wq gets QSCALE folded in. grid (16 ktiles, 48 sel*h).
__global__ __launch_bounds__(256)
void convert_wqkv(const float* __restrict__ Wq, const float* __restrict__ Wk,
                  const float* __restrict__ Wv, ushort* __restrict__ Wt) {
  __shared__ ushort T[64 * 72];
  const int tid = threadIdx.x;
  const int kt = blockIdx.x, sh = blockIdx.y;
  const int sel = sh >> 4, h = sh & 15;
  const float* W = (sel == 0) ? Wq : ((sel == 1) ? Wk : Wv);
  const float qs = (sel == 0) ? QSCALE : 1.0f;
  const int rr = tid >> 4;          // 0..15 (k' row)
  const int rc = (tid & 15) * 4;    // d col (float4)
#pragma unroll
  for (int p = 0; p < 64; p += 16) {
    const float4 f = *(const float4*)(W + (size_t)h * 65536 + (size_t)(kt * 64 + p + rr) * 64 + rc);
    ushort4 u;
    u.x = f2b(f.x * qs); u.y = f2b(f.y * qs); u.z = f2b(f.z * qs); u.w = f2b(f.w * qs);
    *(ushort4*)&T[(p + rr) * 72 + rc] = u;
  }
  __syncthreads();
  const int dd = tid >> 2;          // 0..63 (d)
  const int c16 = (tid & 3) * 16;   // k' base
  sh8 v0, v1;
#pragma unroll
  for (int j = 0; j < 8; j++) v0[j] = (short)T[(c16 + j) * 72 + dd];
#pragma unroll
  for (int j = 0; j < 8; j++) v1[j] = (short)T[(c16 + 8 + j) * 72 + dd];
  ushort* op = Wt + ((size_t)sel * 1024 + h * 64 + dd) * 1024 + kt * 64 + c16;
  *(sh8*)op = v0;
  *(sh8*)(op + 8) = v1;
}

// ---------------- GEMM: 256x256 block, 8 waves (2x4), wave tile 128x64,
// BK=64, 8-phase pipelined schedule (T3+T4), counted vmcnt (never 0 in loop),
// raw s_barrier, setprio around MFMA clusters (T5), XOR-swizzled LDS (T2),
// XCD-bijective block swizzle (T1/m204). K fixed at 1024. C^T fragment trick.
// MODE 0: store bf16.  MODE 1: store f32 + bias.
template <int MODE>
__global__ __launch_bounds__(512, 2)
void gemm256(const ushort* __restrict__ A, const ushort* __restrict__ Bt,
             ushort* __restrict__ Cb, float* __restrict__ Cf,
             const float* __restrict__ bias, int N) {
  constexpr int K = 1024;
  constexpr int NT = K / 64;             // 16 K-tiles
  __shared__ ushort Al[2][256 * 64];     // 64 KB (double-buffered A tile)
  __shared__ ushort Bl[2][256 * 64];     // 64 KB (double-buffered B tile)
  const int tid = threadIdx.x;
  const int lane = tid & 63;
  const int w = tid >> 6;                // 0..7
  const int l15 = lane & 15, quad = lane >> 4;
  const int wm = (w >> 2) * 128;         // WARPS_M = 2
  const int wn = (w & 3) * 64;           // WARPS_N = 4

  // XCD-bijective swizzle (nwg % 8 != 0 here, so m204 form required)
  const int nwg = gridDim.x * gridDim.y;
  const int orig = blockIdx.y * gridDim.x + blockIdx.x;
  const int q = nwg >> 3, r = nwg & 7;
  const int xcd = orig & 7, loc = orig >> 3;
  const int wgid = (xcd < r ? xcd * (q + 1) : r * (q + 1) + (xcd - r) * q) + loc;
  const int m0 = (wgid / gridDim.x) * 256;
  const int n0 = (wgid % gridDim.x) * 256;

  f32x4 acc[8][4];
#pragma unroll
  for (int i = 0; i < 8; i++)
#pragma unroll
    for (int j = 0; j < 4; j++) acc[i][j] = f32x4{0.f, 0.f, 0.f, 0.f};

  // staging: unit = 64 rows x 64 cols (8 KB) = 1 gld16 per thread.
  // thread (r9 = tid>>3, c = tid&7) stores linearly at LDS chunk c of row r9,
  // fetches pre-swizzled global chunk c ^ (r9&7)  (both-sides swizzle, rule 21).
  const int r9 = tid >> 3;                       // 0..63
  const int cs = ((tid & 7) ^ (r9 & 7)) * 8;     // swizzled source chunk (ushorts)
  const ushort* Asrc[4];
#pragma unroll
  for (int i = 0; i < 4; i++)
    Asrc[i] = A + (size_t)min(m0 + i * 64 + r9, MM - 1) * K + cs;
  const ushort* Bsrc = Bt + (size_t)(n0 + r9) * K + cs;      // + i*64*K per unit
  ushort* dA = &Al[0][0] + tid * 8;              // + b*16384 + i*4096
  ushort* dB = &Bl[0][0] + tid * 8;

#define STG_A(i, b, kt) gld16(Asrc[i] + (kt) * 64, dA + (b) * 16384 + (i) * 4096)
#define STG_B(i, b, kt) gld16(Bsrc + (size_t)(i) * (64 * 1024) + (kt) * 64, dB + (b) * 16384 + (i) * 4096)

  // frag-read offsets: global chunk g of row r lives at LDS chunk g ^ (r&7)
  const int swz = l15 & 7;
  const int c0 = (quad ^ swz) * 8;               // ksub 0 (k = quad*8 .. +7)
  const int c1 = ((quad + 4) ^ swz) * 8;         // ksub 1 (k = 32 + quad*8 ..)
  const int arow = (wm + l15) * 64;              // + i*1024 per m-pos
  const int brow = (wn + l15) * 64;              // + j*1024 per n-pos

  // prologue: stage tiles 0 and 1 (8 loads each)
#pragma unroll
  for (int i = 0; i < 4; i++) { STG_A(i, 0, 0); STG_B(i, 0, 0); }
#pragma unroll
  for (int i = 0; i < 4; i++) { STG_A(i, 1, 1); STG_B(i, 1, 1); }
  asm volatile("s_waitcnt vmcnt(8)" ::: "memory");   // tile 0 landed
  SBAR();

  sh8 af[4][2], bf[4][2];
  for (int t = 0; t < NT; ++t) {
    const ushort* Ab = &Al[t & 1][0];
    const ushort* Bb = &Bl[t & 1][0];
    const int pb = t & 1;                 // stage dest = current buffer (t+2 parity)
    const bool st = (t < NT - 2);
    const int kt = t + 2;

    // ---- phase 0: read A-mh0 (8) + B-nh0 (4); MFMA quadrant (mh0,nh0)
#pragma unroll
    for (int i = 0; i < 4; i++) {
      af[i][0] = *(const sh8*)(Ab + arow + i * 1024 + c0);
      af[i][1] = *(const sh8*)(Ab + arow + i * 1024 + c1);
    }
#pragma unroll
    for (int j = 0; j < 2; j++) {
      bf[j][0] = *(const sh8*)(Bb + brow + j * 1024 + c0);
      bf[j][1] = *(const sh8*)(Bb + brow + j * 1024 + c1);
    }
    SBAR(); WAITL(); PRIO1();
#pragma unroll
    for (int i = 0; i < 4; i++)
#pragma unroll
      for (int j = 0; j < 2; j++) {
        acc[i][j] = MFMA16(bf[j][0], af[i][0], acc[i][j]);
        acc[i][j] = MFMA16(bf[j][1], af[i][1], acc[i][j]);
      }
    PRIO0(); SBAR();
    // A quarters {0,2} (rows wm..wm+63 both wave-rows) now dead.

    // ---- phase 1: read B-nh1 (4); stage A q0,q2 of tile t+2; MFMA (mh0,nh1)
#pragma unroll
    for (int j = 2; j < 4; j++) {
      bf[j][0] = *(const sh8*)(Bb + brow + j * 1024 + c0);
      bf[j][1] = *(const sh8*)(Bb + brow + j * 1024 + c1);
    }
    if (st) { STG_A(0, pb, kt); STG_A(2, pb, kt); }
    SBAR(); WAITL(); PRIO1();
#pragma unroll
    for (int i = 0; i < 4; i++)
#pragma unroll
      for (int j = 2; j < 4; j++) {
        acc[i][j] = MFMA16(bf[j][0], af[i][0], acc[i][j]);
        acc[i][j] = MFMA16(bf[j][1], af[i][1], acc[i][j]);
      }
    PRIO0(); SBAR();
    // all B quarters now dead.

    // ---- phase 2: read A-mh1 (8); stage all B quarters; MFMA (mh1,nh1)
#pragma unroll
    for (int i = 0; i < 4; i++) {
      af[i][0] = *(const sh8*)(Ab + arow + (i + 4) * 1024 + c0);
      af[i][1] = *(const sh8*)(Ab + arow + (i + 4) * 1024 + c1);
    }
    if (st) { STG_B(0, pb, kt); STG_B(1, pb, kt); STG_B(2, pb, kt); STG_B(3, pb, kt); }
    SBAR(); WAITL(); PRIO1();
#pragma unroll
    for (int i = 0; i < 4; i++)
#pragma unroll
      for (int j = 2; j < 4; j++) {
        acc[i + 4][j] = MFMA16(bf[j][0], af[i][0], acc[i + 4][j]);
        acc[i + 4][j] = MFMA16(bf[j][1], af[i][1], acc[i + 4][j]);
      }
    PRIO0(); SBAR();
    // A quarters {1,3} now dead.

    // ---- phase 3: stage A q1,q3; MFMA (mh1,nh0); counted vmcnt, barrier
    if (st) { STG_A(1, pb, kt); STG_A(3, pb, kt); }
    SBAR(); PRIO1();
#pragma unroll
    for (int i = 0; i < 4; i++)
#pragma unroll
      for (int j = 0; j < 2; j++) {
        acc[i + 4][j] = MFMA16(bf[j][0], af[i][0], acc[i + 4][j]);
        acc[i + 4][j] = MFMA16(bf[j][1], af[i][1], acc[i + 4][j]);
      }
    PRIO0();
    // tile t+1 (issued last iter) must be landed; tile t+2's 8 may stay in flight
    if (st) { asm volatile("s_waitcnt vmcnt(8)" ::: "memory"); }
    else    { asm volatile("s_waitcnt vmcnt(0)" ::: "memory"); }
    SBAR();
  }
#undef STG_A
#undef STG_B

  // epilogue. C^T fragments: lane l15 -> C row, regs -> 4 consecutive C cols.
#pragma unroll
  for (int i = 0; i < 8; i++) {
    const int row = m0 + wm + i * 16 + l15;
    const bool ok = row < MM;
#pragma unroll
    for (int j = 0; j < 4; j++) {
      const int col0 = n0 + wn + j * 16 + quad * 4;
      if (MODE == 0) {
        uint2 pk;
        pk.x = pk_bf16(acc[i][j][0], acc[i][j][1]);
        pk.y = pk_bf16(acc[i][j][2], acc[i][j][3]);
        if (ok) *(uint2*)&Cb[(size_t)row * N + col0] = pk;
      } else {
        const float4 b4 = *(const float4*)&bias[col0];
        float4 v;
        v.x = acc[i][j][0] + b4.x; v.y = acc[i][j][1] + b4.y;
        v.z = acc[i][j][2] + b4.z; v.w = acc[i][j][3] + b4.w;
        if (ok) *(float4*)&Cf[(size_t)row * N + col0] = v;
      }
    }
  }
}

// ---------------- transpose V: QKV[.,2048+h*64+d] -> Vt[(bh*64+d)][s], zero-padded ----------------
__global__ __launch_bounds__(256)
void transpose_v(const ushort* __restrict__ QKV, ushort* __restrict__ Vtg) {
  __shared__ ushort T[64 * 72];
  const int tid = threadIdx.x;
  const int st = blockIdx.x, bh = blockIdx.y;
  const int b = bh >> 4, h = bh & 15;
  const int sr = tid >> 3;          // 0..31
  const int sc = (tid & 7) * 8;     // d-chunk
#pragma unroll
  for (int p = 0; p < 64; p += 32) {
    const int s = st * 64 + p + sr;
    uint4 d = uint4{0u, 0u, 0u, 0u};
    if (s < SS) d = *(const uint4*)(QKV + ((size_t)b * SS + s) * 3072 + 2048 + h * 64 + sc);
    *(uint4*)&T[(p + sr) * 72 + sc] = d;
  }
  __syncthreads();
  const int dd = tid >> 2;          // 0..63
  const int s16 = (tid & 3) * 16;
  sh8 v0, v1;
#pragma unroll
  for (int j = 0; j < 8; j++) v0[j] = (short)T[(s16 + j) * 72 + dd];
#pragma unroll
  for (int j = 0; j < 8; j++) v1[j] = (short)T[(s16 + 8 + j) * 72 + dd];
  ushort* outp = Vtg + ((size_t)bh * 64 + dd) * SPAD + st * 64 + s16;
  *(sh8*)outp = v0;
  *(sh8*)(outp + 8) = v1;
}

// ---------------- flash attention (one-pass softmax, 32 q-rows/wave) -------------
// grid: (5 qblocks of 128, 512 bh). K/V staged via gld16 into swizzled 64-stride
// tiles; each wave reuses K/V frags across 2 q-groups of 16.
// S^T = K·Q^T; O^T = V^T·P^T; l = ones·P^T (all MFMA, no shuffles).
__global__ __launch_bounds__(256)
void flash_attn(const ushort* __restrict__ QKV, const ushort* __restrict__ Vtg,
                ushort* __restrict__ Ob) {
  __shared__ ushort Kl[64 * 64];    // row = kpos, chunk-swizzled
  __shared__ ushort Vl[64 * 64];    // row = d,    chunk-swizzled
  __shared__ ushort Pl[128 * 72];   // row = q (wave-local 32 rows), col = kpos
  const int tid = threadIdx.x;
  const int lane = tid & 63, w = tid >> 6;
  const int l15 = lane & 15, quad = lane >> 4;
  const int qb = blockIdx.x, bh = blockIdx.y;
  const int b = bh >> 4, h = bh & 15;

  sh8 qf[2][2];
#pragma unroll
  for (int g = 0; g < 2; g++) {
    const int qr = qb * 128 + w * 32 + g * 16 + l15;
    const ushort* qrow = QKV + ((size_t)b * SS + min(qr, SS - 1)) * 3072 + h * 64;
    qf[g][0] = *(const sh8*)(qrow + quad * 8);
    qf[g][1] = *(const sh8*)(qrow + 32 + quad * 8);
  }

  sh8 ones;
#pragma unroll
  for (int j = 0; j < 8; j++) ones[j] = (short)0x3F80;   // bf16 1.0

  f32x4 o[2][4];
  f32x4 acc_l[2];
#pragma unroll
  for (int g = 0; g < 2; g++) {
    acc_l[g] = f32x4{0.f, 0.f, 0.f, 0.f};
#pragma unroll
    for (int t = 0; t < 4; t++) o[g][t] = f32x4{0.f, 0.f, 0.f, 0.f};
  }

  // staging: 2 gld16 per matrix; unit u = i*256+tid, row=u>>3, cc=u&7, swizzled source
  const int r0 = tid >> 3;                           // 0..31
  const int swzs = ((tid & 7) ^ (r0 & 7)) * 8;
  const ushort* Kg = QKV + (size_t)b * SS * 3072 + 1024 + h * 64 + swzs;
  const ushort* Vg0 = Vtg + ((size_t)bh * 64 + r0) * SPAD + swzs;
  const ushort* Vg1 = Vtg + ((size_t)bh * 64 + 32 + r0) * SPAD + swzs;
  ushort* lK0 = &Kl[tid * 8];
  ushort* lK1 = &Kl[(256 + tid) * 8];
  ushort* lV0 = &Vl[tid * 8];
  ushort* lV1 = &Vl[(256 + tid) * 8];

  const int swz = l15 & 7;
  const int ca0 = (quad ^ swz) * 8;
  const int ca1 = ((quad + 4) ^ swz) * 8;
  ushort* plw[2] = { &Pl[(w * 32 + l15) * 72], &Pl[(w * 32 + 16 + l15) * 72] };

  for (int kt = 0; kt < 10; kt++) {
    const int kb = kt * 64;
    __syncthreads();
    gld16(Kg + (size_t)min(kb + r0, SS - 1) * 3072, lK0);
    gld16(Kg + (size_t)min(kb + 32 + r0, SS - 1) * 3072, lK1);
    gld16(Vg0 + kb, lV0);
    gld16(Vg1 + kb, lV1);
    __syncthreads();

#pragma unroll
    for (int tn = 0; tn < 4; tn++) {
      const int kr = tn * 16 + l15;
      const sh8 k0 = *(const sh8*)&Kl[kr * 64 + ca0];
      const sh8 k1 = *(const sh8*)&Kl[kr * 64 + ca1];
#pragma unroll
      for (int g = 0; g < 2; g++) {
        f32x4 s = f32x4{0.f, 0.f, 0.f, 0.f};
        s = MFMA16(k0, qf[g][0], s);      // S^T: row=kpos=tn*16+quad*4+r, col=q=l15
        s = MFMA16(k1, qf[g][1], s);
        if (kt == 9) {                    // kb=576: only kpos-local 0 is valid
#pragma unroll
          for (int r = 0; r < 4; r++)
            if ((tn * 16 + quad * 4 + r) != 0) s[r] = -1e30f;
        }
        uint2 pp;
        pp.x = pk_bf16(EXP2F(s[0]), EXP2F(s[1]));
        pp.y = pk_bf16(EXP2F(s[2]), EXP2F(s[3]));
        *(uint2*)(plw[g] + tn * 16 + quad * 4) = pp;
      }
    }
    // wave-local P rows: no barrier needed between write and read
    sh8 pa[2][2];
#pragma unroll
    for (int g = 0; g < 2; g++) {
      pa[g][0] = *(const sh8*)(plw[g] + quad * 8);     // B: n=q=l15, k=kpos
      pa[g][1] = *(const sh8*)(plw[g] + 32 + quad * 8);
      acc_l[g] = MFMA16(ones, pa[g][0], acc_l[g]);
      acc_l[g] = MFMA16(ones, pa[g][1], acc_l[g]);
    }
#pragma unroll
    for (int t = 0; t < 4; t++) {
      const int vr = t * 16 + l15;
      const sh8 v0 = *(const sh8*)&Vl[vr * 64 + ca0];  // A: m=d, k=kpos
      const sh8 v1 = *(const sh8*)&Vl[vr * 64 + ca1];
#pragma unroll
      for (int g = 0; g < 2; g++) {
        o[g][t] = MFMA16(v0, pa[g][0], o[g][t]);       // O^T: row=d, col=q=l15
        o[g][t] = MFMA16(v1, pa[g][1], o[g][t]);
      }
    }
  }

#pragma unroll
  for (int g = 0; g < 2; g++) {
    const float inv = 1.0f / acc_l[g][0];
    const int s = qb * 128 + w * 32 + g * 16 + l15;
    if (s < SS) {
      ushort* op = Ob + ((size_t)b * SS + s) * 1024 + h * 64 + quad * 4;
#pragma unroll
      for (int t = 0; t < 4; t++) {
        uint2 ov;
        ov.x = pk_bf16(o[g][t][0] * inv, o[g][t][1] * inv);
        ov.y = pk_bf16(o[g][t][2] * inv, o[g][t][3] * inv);
        *(uint2*)(op + t * 16) = ov;
      }
    }
  }
}

// ---------------- launch ----------------
extern "C" void kernel_launch(void* const* d_in, const int* in_sizes, int n_in,
                              void* d_out, int out_size, void* d_ws, size_t ws_size,
                              hipStream_t stream) {
  const float* x  = (const float*)d_in[0];
  const float* Wq = (const float*)d_in[1];
  const float* Wk = (const float*)d_in[2];
  const float* Wv = (const float*)d_in[3];
  const float* Wo = (const float*)d_in[4];
  const float* bo = (const float*)d_in[5];
  float* out = (float*)d_out;

  // workspace layout (bf16 elements); Ob reuses Xb (dead after GEMM1)
  ushort* Xb  = (ushort*)d_ws;                      // MM*1024
  ushort* Wt  = Xb  + (size_t)MM * 1024;            // 3072*1024
  ushort* Wob = Wt  + (size_t)3072 * 1024;          // 1024*1024
  ushort* QKV = Wob + (size_t)1024 * 1024;          // MM*3072
  ushort* Vtg = QKV + (size_t)MM * 3072;            // 512*64*640
  ushort* Ob  = Xb;

  convert2_f32_bf16<<<4096, 256, 0, stream>>>(x, Xb, MM * 1024 / 4, Wo, Wob, 1024 * 1024 / 4);
  convert_wqkv<<<dim3(16, 48), 256, 0, stream>>>(Wq, Wk, Wv, Wt);
  gemm256<0><<<dim3(12, 73), 512, 0, stream>>>(Xb, Wt, QKV, nullptr, nullptr, 3072);
  transpose_v<<<dim3(10, 512), 256, 0, stream>>>(QKV, Vtg);
  flash_attn<<<dim3(5, 512), 256, 0, stream>>>(QKV, Vtg, Ob);
  gemm256<1><<<dim3(4, 73), 512, 0, stream>>>(Ob, Wob, nullptr, out, bo, 1024);
}